// Round 1
// baseline (106.824 us; speedup 1.0000x reference)
//
#include <hip/hip_runtime.h>
#include <math.h>

#define N_NODES 8192
#define KNN 9
#define TILE 128

// Fully-unrolled, statically-indexed carry-bubble insert into sorted-ascending
// top-9 (strict <, so equal keys keep the incumbent = lower index first, which
// matches jax.lax.top_k tie-breaking when candidates arrive in ascending index
// order).
__device__ __forceinline__ void insert9(float (&td)[9], int (&ti)[9], float d, int idx) {
  float cd = d; int ci = idx;
#pragma unroll
  for (int k = 0; k < 9; ++k) {
    bool c = cd < td[k];
    float od = td[k]; int oi = ti[k];
    td[k] = c ? cd : od;  ti[k] = c ? ci : oi;
    cd = c ? od : cd;     ci = c ? oi : ci;
  }
}

// K1: x[B,C,H,W] -> xf[N,C]; sq[n] = ||xf[n]||^2 ; zero deg
__global__ __launch_bounds__(256) void k_prep(const float* __restrict__ x,
                                              float* __restrict__ xf,
                                              float* __restrict__ sq,
                                              int* __restrict__ deg) {
  int tid = blockIdx.x * 256 + threadIdx.x;   // tid = n*64 + c  (wave = one n, lane = c)
  int n = tid >> 6, c = tid & 63;
  int b = n >> 10, hw = n & 1023;
  float v = x[(b * 64 + c) * 1024 + hw];
  xf[tid] = v;
  float s = v * v;
#pragma unroll
  for (int m = 1; m < 64; m <<= 1) s += __shfl_xor(s, m);
  if (c == 0) sq[n] = s;
  if (tid < N_NODES) deg[tid] = 0;
}

// K2: per-batch chunked KNN. grid = (32 query-chunks of 256, P candidate-chunks).
// Each thread owns one query (vector in 64 VGPRs), scans its batch's candidate
// chunk from a broadcast LDS tile, keeps a private sorted top-9.
__global__ __launch_bounds__(256) void k_knn(const float* __restrict__ xf,
                                             const float* __restrict__ sq,
                                             float* __restrict__ pd,
                                             int* __restrict__ pi, int P) {
  __shared__ float lx[TILE * 64];
  __shared__ float lsq[TILE];
  const int qbase = blockIdx.x * 256;
  const int p = blockIdx.y;
  const int q = qbase + (int)threadIdx.x;
  // batch of this block's queries (256-chunks never straddle batch boundaries;
  // sole exception is node 8191 = batch 8, masked below)
  const int b = (8 * qbase) / 8191;
  const int bstart = (b * 8191 + 7) / 8;            // ceil(b*8191/8)
  int bend = ((b + 1) * 8191 + 7) / 8;              // start of next batch
  if (bend > N_NODES - 1) bend = N_NODES - 1;       // exclude node 8191 (batch 8)

  const int len = bend - bstart;
  const int csz = (len + P - 1) / P;
  const int cs = bstart + p * csz;
  const int ce = min(cs + csz, bend);

  float qv[64];
  const float4* qp = reinterpret_cast<const float4*>(xf + (size_t)q * 64);
#pragma unroll
  for (int i = 0; i < 16; ++i) {
    float4 v = qp[i];
    qv[4 * i + 0] = v.x; qv[4 * i + 1] = v.y; qv[4 * i + 2] = v.z; qv[4 * i + 3] = v.w;
  }
  const float sqq = sq[q];

  float td[9]; int ti[9];
#pragma unroll
  for (int k = 0; k < 9; ++k) { td[k] = 3.0e38f; ti[k] = 0x7fffffff; }

  for (int ts = cs; ts < ce; ts += TILE) {
    const int tc = min(TILE, ce - ts);
    __syncthreads();
    const float4* src4 = reinterpret_cast<const float4*>(xf + (size_t)ts * 64);
    float4* dst4 = reinterpret_cast<float4*>(lx);
    for (int t = threadIdx.x; t < tc * 16; t += 256) dst4[t] = src4[t];
    for (int t = threadIdx.x; t < tc; t += 256) lsq[t] = sq[ts + t];
    __syncthreads();
#pragma unroll 2
    for (int j = 0; j < tc; ++j) {
      const float4* cj = reinterpret_cast<const float4*>(lx + j * 64);
      float a0 = 0.f, a1 = 0.f, a2 = 0.f, a3 = 0.f;
#pragma unroll
      for (int i = 0; i < 16; ++i) {
        float4 v = cj[i];
        a0 = fmaf(qv[4 * i + 0], v.x, a0);
        a1 = fmaf(qv[4 * i + 1], v.y, a1);
        a2 = fmaf(qv[4 * i + 2], v.z, a2);
        a3 = fmaf(qv[4 * i + 3], v.w, a3);
      }
      float dot = (a0 + a1) + (a2 + a3);
      float d2 = fmaf(-2.f, dot, sqq + lsq[j]);
      if (d2 < td[8]) insert9(td, ti, d2, ts + j);
    }
  }
  if (q != N_NODES - 1) {
    int base = (p * N_NODES + q) * KNN;
#pragma unroll
    for (int k = 0; k < 9; ++k) { pd[base + k] = td[k]; pi[base + k] = ti[k]; }
  }
}

// K3: merge P sorted partial lists -> final 9; count degrees (src != dst).
__global__ __launch_bounds__(128) void k_merge(const float* __restrict__ pd,
                                               const int* __restrict__ pi,
                                               int* __restrict__ idxf,
                                               int* __restrict__ deg, int P) {
  int q = blockIdx.x * 128 + threadIdx.x;
  float td[9]; int ti[9];
#pragma unroll
  for (int k = 0; k < 9; ++k) { td[k] = 3.0e38f; ti[k] = 0x7fffffff; }
  if (q == N_NODES - 1) {
    // batch 8 = {8191}: self first, then -inf ties filled with indices 0..7
    ti[0] = N_NODES - 1;
#pragma unroll
    for (int k = 1; k < 9; ++k) ti[k] = k - 1;
  } else {
    for (int p = 0; p < P; ++p) {
      int base = (p * N_NODES + q) * KNN;
#pragma unroll
      for (int k = 0; k < 9; ++k) {
        float cd = pd[base + k];
        if (!(cd < td[8])) break;   // list sorted: rest can't insert either
        insert9(td, ti, cd, pi[base + k]);
      }
    }
  }
#pragma unroll
  for (int k = 0; k < 9; ++k) idxf[q * KNN + k] = ti[k];
#pragma unroll
  for (int k = 0; k < 9; ++k) {
    int s = ti[k];
    if (s != q) atomicAdd(&deg[s], 1);
  }
}

// K4: g[t] = sum_k (-dis[s_k] * dis[t]) * xf[s_k]   (s_k != t)
__global__ __launch_bounds__(256) void k_gather(const float* __restrict__ xf,
                                                const int* __restrict__ idxf,
                                                const int* __restrict__ deg,
                                                float* __restrict__ g) {
  int tid = blockIdx.x * 256 + threadIdx.x;   // n*16 + c4
  int n = tid >> 4, c4 = tid & 15;
  int dt = deg[n];
  float dis_t = dt > 0 ? 1.f / sqrtf((float)dt) : 0.f;
  float ax = 0.f, ay = 0.f, az = 0.f, aw = 0.f;
#pragma unroll
  for (int k = 0; k < 9; ++k) {
    int s = idxf[n * KNN + k];
    if (s == n) continue;                      // self loop: w=0 -> norm 0
    int ds = deg[s];
    float dis_s = ds > 0 ? 1.f / sqrtf((float)ds) : 0.f;
    float w = -dis_s * dis_t;
    float4 v = reinterpret_cast<const float4*>(xf + (size_t)s * 64)[c4];
    ax = fmaf(w, v.x, ax); ay = fmaf(w, v.y, ay);
    az = fmaf(w, v.z, az); aw = fmaf(w, v.w, aw);
  }
  float4 r; r.x = ax; r.y = ay; r.z = az; r.w = aw;
  reinterpret_cast<float4*>(g)[tid] = r;
}

// K5: out = xf @ W0 + g @ W1 + bias   ([8192,64]@[64,64] x2, LDS-staged weights)
__global__ __launch_bounds__(256) void k_out(const float* __restrict__ xf,
                                             const float* __restrict__ g,
                                             const float* __restrict__ W0,
                                             const float* __restrict__ W1,
                                             const float* __restrict__ bias,
                                             float* __restrict__ out) {
  __shared__ float w0[64 * 64];
  __shared__ float w1[64 * 64];
  __shared__ float sx[16 * 65];   // +1 pad: kills 4-way bank conflict on row reads
  __shared__ float sg[16 * 65];
  int nb = blockIdx.x * 16;
  float4* w04 = reinterpret_cast<float4*>(w0);
  float4* w14 = reinterpret_cast<float4*>(w1);
  const float4* W04 = reinterpret_cast<const float4*>(W0);
  const float4* W14 = reinterpret_cast<const float4*>(W1);
  for (int t = threadIdx.x; t < 1024; t += 256) { w04[t] = W04[t]; w14[t] = W14[t]; }
  for (int t = threadIdx.x; t < 1024; t += 256) {
    int ln = t >> 6, c = t & 63;
    sx[ln * 65 + c] = xf[(size_t)(nb + ln) * 64 + c];
    sg[ln * 65 + c] = g[(size_t)(nb + ln) * 64 + c];
  }
  __syncthreads();
  int ln = threadIdx.x >> 4, o4 = threadIdx.x & 15;
  float4 acc = reinterpret_cast<const float4*>(bias)[o4];
#pragma unroll
  for (int c = 0; c < 64; ++c) {
    float xv = sx[ln * 65 + c];
    float gv = sg[ln * 65 + c];
    float4 v0 = reinterpret_cast<const float4*>(w0 + c * 64)[o4];
    float4 v1 = reinterpret_cast<const float4*>(w1 + c * 64)[o4];
    acc.x = fmaf(xv, v0.x, acc.x); acc.y = fmaf(xv, v0.y, acc.y);
    acc.z = fmaf(xv, v0.z, acc.z); acc.w = fmaf(xv, v0.w, acc.w);
    acc.x = fmaf(gv, v1.x, acc.x); acc.y = fmaf(gv, v1.y, acc.y);
    acc.z = fmaf(gv, v1.z, acc.z); acc.w = fmaf(gv, v1.w, acc.w);
  }
  reinterpret_cast<float4*>(out)[(size_t)(nb + ln) * 16 + o4] = acc;
}

extern "C" void kernel_launch(void* const* d_in, const int* in_sizes, int n_in,
                              void* d_out, int out_size, void* d_ws, size_t ws_size,
                              hipStream_t stream) {
  const float* x    = (const float*)d_in[0];
  const float* W0   = (const float*)d_in[1];
  const float* W1   = (const float*)d_in[2];
  const float* bias = (const float*)d_in[3];
  float* out = (float*)d_out;
  char* ws = (char*)d_ws;

  // workspace layout
  float* xf   = (float*)(ws);                       // 8192*64*4 = 2,097,152
  float* sq   = (float*)(ws + 2097152);             // 32,768
  int*   deg  = (int*)  (ws + 2129920);             // 32,768
  int*   idxf = (int*)  (ws + 2162688);             // 8192*9*4 = 294,912
  char*  pbase = ws + 2457600;                      // partials; later reused for g

  int P = 8;
  while (P > 1) {
    size_t parts = (size_t)P * N_NODES * KNN * 8;
    size_t need = 2457600 + (parts > 2097152 ? parts : (size_t)2097152);
    if (need <= ws_size) break;
    P >>= 1;
  }
  float* pd = (float*)pbase;
  int*   pi = (int*)(pbase + (size_t)P * N_NODES * KNN * 4);
  float* g  = (float*)pbase;  // aliases pd: pd dead after k_merge

  k_prep  <<<2048, 256, 0, stream>>>(x, xf, sq, deg);
  k_knn   <<<dim3(32, P), 256, 0, stream>>>(xf, sq, pd, pi, P);
  k_merge <<<64, 128, 0, stream>>>(pd, pi, idxf, deg, P);
  k_gather<<<512, 256, 0, stream>>>(xf, idxf, deg, g);
  k_out   <<<512, 256, 0, stream>>>(xf, g, W0, W1, bias, out);
}